// Round 18
// baseline (57.342 us; speedup 1.0000x reference)
//
#include <hip/hip_runtime.h>
#include <math.h>

namespace {
constexpr int D = 256;
constexpr int H = 8;
constexpr int HD = 32;
constexpr int B = 8;
constexpr int S = 127;
constexpr int N = 128;
constexpr float LN_EPS = 1e-5f;

// ws layout (float offsets). P1T/P2T are stored PACKED:
// element (b, c, i) at (b*64 + (c>>2))*512 + i*4 + (c&3)  -> float4 over c for fixed i.
// P1T rows INCLUDE eb1 (folded at kA time).
constexpr int WS_P1T = 0;                  // B*D*N
constexpr int WS_P2T = WS_P1T + B * D * N; // B*D*N
constexpr int WS_V   = WS_P2T + B * D * N; // B*N*D (row-major)
constexpr int WS_AQ  = WS_V + B * N * D;   // B*H*N
constexpr int WS_AK  = WS_AQ + B * H * N;  // B*H*N
constexpr int WS_FQK = WS_AK + B * H * N;  // D*16 (wq-fold | wk-fold)
constexpr int WS_V2  = WS_FQK + D * 16;    // H*D (transposed: [h][c])
constexpr int WS_BF  = WS_V2 + D * H;      // 32 (bq-fold[8], bk-fold[8], be-fold[8])
constexpr int WS_ST  = WS_BF + 32;         // B*4*N row stats: S1,Q1,S2,Q2 (incl eb1 in P1)
constexpr int WS_RSTD = WS_ST + B * 512;   // B*N*N per-pair 1/std
constexpr int WS_MB   = WS_RSTD + B * N * N; // B*N*N per-pair -mean/std

typedef float f32x2 __attribute__((ext_vector_type(2)));
union F4 { float4 v; f32x2 h[2]; float f[4]; };
} // namespace

// K1: fold wq/wk with attn_w[:32]/[32:64] -> FQK (D x 16), ew2 with attn_w[64:96]
// -> V2T (H x D), plus bias folds. Thread-per-output.
__global__ __launch_bounds__(256) void k1_fold(
    const float* __restrict__ wq, const float* __restrict__ wk,
    const float* __restrict__ ew2, const float* __restrict__ bq,
    const float* __restrict__ bk, const float* __restrict__ eb2,
    const float* __restrict__ attn_w, float* __restrict__ ws) {
  float* FQK = ws + WS_FQK;
  float* V2T = ws + WS_V2;
  float* BF  = ws + WS_BF;
  const int tg = blockIdx.x * 256 + threadIdx.x;
  if (tg < 6144) {
    const int mat = tg >> 11;
    const int rem = tg & 2047;
    const int c = rem >> 3;
    const int h = rem & 7;
    const float* W = (mat == 0) ? wq : (mat == 1) ? wk : ew2;
    const float* aw = attn_w + mat * HD;
    const float* wrow = W + c * D + h * HD;
    float s = 0.f;
#pragma unroll
    for (int d = 0; d < HD; ++d) s = fmaf(wrow[d], aw[d], s);
    if (mat < 2) FQK[c * 16 + mat * 8 + h] = s;
    else         V2T[h * D + c] = s;
  } else if (tg < 6168) {
    const int idx = tg - 6144;
    const int mat = idx >> 3;
    const int h = idx & 7;
    const float* bias = (mat == 0) ? bq : (mat == 1) ? bk : eb2;
    const float* aw = attn_w + mat * HD;
    float s = 0.f;
#pragma unroll
    for (int d = 0; d < HD; ++d) s = fmaf(bias[h * HD + d], aw[d], s);
    BF[mat * 8 + h] = s;
  }
}

// KA: role 0 (blocks 0..127): 8 desc rows/block -> P1/P2 packed (+eb1 into P1)
// + row stats. role 1 (blocks 128..255): 8 nv rows/block -> V + aq/ak.
__global__ __launch_bounds__(512) void kA_pre(
    const float* __restrict__ desc, const float* __restrict__ ew1,
    const float* __restrict__ eb1,
    const float* __restrict__ nv, const float* __restrict__ wv,
    const float* __restrict__ bv, float* __restrict__ ws) {
  const int blk = blockIdx.x;
  const int t = threadIdx.x;
  __shared__ float rows[8][264];          // 8.4 KB
  __shared__ float red[8][4][64][4];      // 32 KB
  __shared__ float fqks[D * 16];          // 16 KB (role 1)
  __shared__ float aqred2[2][128];

  if (blk < 128) {
    // ---- role 0 ----
    float* P1Tf = ws + WS_P1T;
    float* P2Tf = ws + WS_P2T;
    const int b = blk >> 4;
    const int i0 = (blk & 15) * 8;
    {
      const int r = t >> 6, c4 = t & 63;
      const int row = i0 + r;
      F4 dv;
      if (row < S) dv.v = *(const float4*)&desc[(b * S + row) * D + c4 * 4];
      else         dv.v = make_float4(0.f, 0.f, 0.f, 0.f);
      *(float4*)&rows[r][c4 * 4] = dv.v;
    }
    __syncthreads();
    const int o4 = t & 63;
    const int grp = t >> 6;
    const int m = grp >> 2;          // 0: ew1[:D] (P1), 1: ew1[D:] (P2)
    const int q = grp & 3;           // c2 quarter
    const float* W = ew1 + m * D * D;
    F4 acc[8];
#pragma unroll
    for (int r = 0; r < 8; ++r) acc[r].v = make_float4(0.f, 0.f, 0.f, 0.f);
    for (int cc = 0; cc < 64; ++cc) {
      const int c2 = q * 64 + cc;
      F4 w; w.v = *(const float4*)&W[c2 * D + o4 * 4];
#pragma unroll
      for (int r = 0; r < 8; ++r) {
        const float s = rows[r][c2];
#pragma unroll
        for (int e = 0; e < 4; ++e) acc[r].f[e] = fmaf(s, w.f[e], acc[r].f[e]);
      }
    }
#pragma unroll
    for (int mm = 0; mm < 2; ++mm) {
      if (m == mm) {
#pragma unroll
        for (int r = 0; r < 8; ++r) *(float4*)&red[r][q][o4][0] = acc[r].v;
      }
      __syncthreads();
      {
        const int r = t >> 6;        // one wave per row; lane = o4
        F4 s; s.v = make_float4(0.f, 0.f, 0.f, 0.f);
#pragma unroll
        for (int g = 0; g < 4; ++g) {
          F4 p; p.v = *(const float4*)&red[r][g][o4][0];
#pragma unroll
          for (int e = 0; e < 4; ++e) s.f[e] += p.f[e];
        }
        if (mm == 0) {
          F4 eb; eb.v = *(const float4*)&eb1[o4 * 4];
#pragma unroll
          for (int e = 0; e < 4; ++e) s.f[e] += eb.f[e];
        }
        const int row = i0 + r;
        float* PT = (mm == 0) ? P1Tf : P2Tf;
        if (row < S) *(float4*)&PT[(b * 64 + o4) * 512 + row * 4] = s.v;
        float sv = 0.f, qv = 0.f;
#pragma unroll
        for (int e = 0; e < 4; ++e) {
          sv += s.f[e];
          qv = fmaf(s.f[e], s.f[e], qv);
        }
#pragma unroll
        for (int o = 1; o < 64; o <<= 1) {
          sv += __shfl_xor(sv, o);
          qv += __shfl_xor(qv, o);
        }
        if (o4 == 0 && row < S) {
          float* STW = ws + WS_ST + b * 512 + mm * 256;
          STW[row] = sv;
          STW[128 + row] = qv;
        }
      }
      __syncthreads();
    }
  } else {
    // ---- role 1 ----
    float* Vf  = ws + WS_V;
    float* AQ  = ws + WS_AQ;
    float* AK  = ws + WS_AK;
    const float* BF = ws + WS_BF;
    const int blk2 = blk - 128;
    const int b = blk2 >> 4;
    const int j0 = (blk2 & 15) * 8;
    {
      const int r = t >> 6, c4 = t & 63;
      *(float4*)&rows[r][c4 * 4] =
          *(const float4*)&nv[(b * N + j0 + r) * D + c4 * 4];
      float4* fq4 = (float4*)fqks;
      const float4* FQK4 = (const float4*)(ws + WS_FQK);
      fq4[t] = FQK4[t];
      fq4[512 + t] = FQK4[512 + t];
    }
    __syncthreads();
    if (t < 256) {
      // waves 0-3: V = nv @ wv partials (channel quarter q)
      const int o4 = t & 63, q = t >> 6;
      F4 acc[8];
#pragma unroll
      for (int r = 0; r < 8; ++r) acc[r].v = make_float4(0.f, 0.f, 0.f, 0.f);
      for (int cc = 0; cc < 64; ++cc) {
        const int c2 = q * 64 + cc;
        F4 w; w.v = *(const float4*)&wv[c2 * D + o4 * 4];
#pragma unroll
        for (int r = 0; r < 8; ++r) {
          const float s = rows[r][c2];
#pragma unroll
          for (int e = 0; e < 4; ++e)
            acc[r].f[e] = fmaf(s, w.f[e], acc[r].f[e]);
        }
      }
#pragma unroll
      for (int r = 0; r < 8; ++r) *(float4*)&red[r][q][o4][0] = acc[r].v;
    } else {
      // waves 4-7: aq/ak via LDS FQK
      const int idx = t - 256;
      const int il = idx >> 5;           // row 0..7
      const int oi = idx & 15;           // output (aq|ak)
      const int ch = (idx >> 4) & 1;     // channel half
      float s = 0.f;
      for (int c = ch * 128; c < ch * 128 + 128; ++c)
        s = fmaf(rows[il][c], fqks[c * 16 + oi], s);
      aqred2[ch][il * 16 + oi] = s;
    }
    __syncthreads();
    {
      const int r = t >> 6, o4 = t & 63;
      F4 s; s.v = make_float4(0.f, 0.f, 0.f, 0.f);
#pragma unroll
      for (int g = 0; g < 4; ++g) {
        F4 p; p.v = *(const float4*)&red[r][g][o4][0];
#pragma unroll
        for (int e = 0; e < 4; ++e) s.f[e] += p.f[e];
      }
      F4 b4; b4.v = *(const float4*)&bv[o4 * 4];
#pragma unroll
      for (int e = 0; e < 4; ++e) s.f[e] += b4.f[e];
      *(float4*)&Vf[(b * N + j0 + r) * D + o4 * 4] = s.v;
    }
    if (t < 128) {
      const int il = t >> 4, oi = t & 15;
      const float s2 = aqred2[0][t] + aqred2[1][t] + BF[oi];
      if (oi < 8) AQ[(b * H + oi) * N + j0 + il] = s2;
      else        AK[(b * H + (oi - 8)) * N + j0 + il] = s2;
    }
  }
}

// KG: G = P1 . P2 per (ip,jp) pair via reg-cached P2 slices, then fold with
// row stats ST into per-pair rstd / mB. grid 256 (XCD-swizzled), 512 threads.
__global__ __launch_bounds__(512) void kG_stats(float* __restrict__ ws) {
  const int bid = blockIdx.x;
  const int wg = (bid & 7) * 32 + (bid >> 3);   // one b per XCD
  const int b = wg >> 5;
  const int ip0 = (wg & 31) * 4;
  const int t = threadIdx.x;
  const int jp = t & 127;
  const int cg = t >> 7;

  __shared__ float p1t[1024];        // [4][256]
  __shared__ float gred[4][4][128];  // [cg][r][jp]

  const float* P1Tf = ws + WS_P1T;
  const float4* P24 = reinterpret_cast<const float4*>(ws + WS_P2T);
  const float* ST = ws + WS_ST + b * 512;
  float* RST = ws + WS_RSTD + b * N * N;
  float* MBP = ws + WS_MB + b * N * N;
  const int base4 = b * 64 * 128;

  for (int k = t; k < 1024; k += 512) {
    const int r = k >> 8, c = k & 255;
    const int row = ip0 + r;
    p1t[r * 256 + c] = (row < S)
        ? P1Tf[(b * 64 + (c >> 2)) * 512 + row * 4 + (c & 3)] : 0.f;
  }
  F4 pp[16];
#pragma unroll
  for (int cc = 0; cc < 16; ++cc)
    pp[cc].v = P24[base4 + (cg * 16 + cc) * 128 + jp];
  __syncthreads();

  float g[4] = {0.f, 0.f, 0.f, 0.f};
#pragma unroll
  for (int cc = 0; cc < 16; ++cc) {
    const int c4 = cg * 16 + cc;
#pragma unroll
    for (int r = 0; r < 4; ++r) {
      F4 p1; p1.v = *(const float4*)&p1t[r * 256 + c4 * 4];
      g[r] = fmaf(pp[cc].f[0], p1.f[0], g[r]);
      g[r] = fmaf(pp[cc].f[1], p1.f[1], g[r]);
      g[r] = fmaf(pp[cc].f[2], p1.f[2], g[r]);
      g[r] = fmaf(pp[cc].f[3], p1.f[3], g[r]);
    }
  }
#pragma unroll
  for (int r = 0; r < 4; ++r) gred[cg][r][jp] = g[r];
  __syncthreads();
  {
    const int r2 = t >> 7, jp2 = t & 127;
    const float G = gred[0][r2][jp2] + gred[1][r2][jp2]
                  + gred[2][r2][jp2] + gred[3][r2][jp2];
    const int ip = ip0 + r2;
    const float S1 = ST[0 * 128 + ip], Q1 = ST[1 * 128 + ip];
    const float S2 = ST[2 * 128 + jp2], Q2 = ST[3 * 128 + jp2];
    const float mean = (S1 + S2) * (1.f / 256.f);
    const float var = (Q1 + Q2 + 2.f * G) * (1.f / 256.f) - mean * mean;
    const float rstd = 1.f / sqrtf(var + LN_EPS);
    RST[ip * N + jp2] = rstd;
    MBP[ip * N + jp2] = -mean * rstd;
  }
}

// K4: edge-MLP dot -> scores -> softmax -> attn write (R14 structure).
// grid B*32 (XCD-swizzled): block = (b, 4-row i-tile). 512 threads:
// jl = t&127, cq = t>>7 (channel quarter; heads {2cq,2cq+1} for softmax).
// vs R14: ALL 16 p2 float4 preloaded into registers before loop B (one
// latency instead of a 16-deep chained prefetch), enabled by
// __launch_bounds__(512,1) lifting the 64-VGPR heuristic cap. Only 1
// block/CU is resident (grid 256), so extra VGPR costs no occupancy.
__global__ __launch_bounds__(512, 1) void k4_attn(
    const float* __restrict__ ws,
    const float* __restrict__ ln_g, const float* __restrict__ ln_b,
    const float* __restrict__ attn_bp, float* __restrict__ attnp) {
  const int bid = blockIdx.x;
  const int wg = (bid & 7) * 32 + (bid >> 3);   // bijective; one b per XCD
  const int b = wg >> 5;
  const int i0 = (wg & 31) * 4;
  const int t = threadIdx.x;
  const int jl = t & 127;
  const int cq = t >> 7;

  __shared__ float v2s[H * D];       // 8 KB
  __shared__ float gbs[2 * D];       // 2 KB (ln_g | ln_b)
  __shared__ float p1e[4][D];        // 4 KB
  __shared__ float dsh[4][128][9];   // 18 KB, stride 9 = conflict-free
  __shared__ float aqs[4][8];
  __shared__ float redm[8][2], reds[8][2];

  const float* P1Tf = ws + WS_P1T;
  const float* AQ   = ws + WS_AQ;
  const float* AK   = ws + WS_AK;
  const float* BF   = ws + WS_BF;
  const float* v2p  = ws + WS_V2;
  const float* RST  = ws + WS_RSTD + b * N * N;
  const float* MBP  = ws + WS_MB + b * N * N;

  // stage uniform operands into LDS
  reinterpret_cast<float4*>(v2s)[t] = reinterpret_cast<const float4*>(v2p)[t];
  if (t < 256) { gbs[t] = ln_g[t]; gbs[256 + t] = ln_b[t]; }
  for (int k = t; k < 4 * D; k += 512) {
    const int r = k >> 8, c = k & 255;
    const int row = i0 + r - 1;
    p1e[r][c] = (row >= 0)
        ? P1Tf[(b * 64 + (c >> 2)) * 512 + row * 4 + (c & 3)] : 0.f;
  }
  if (t < 32) {
    const int r = t >> 3, h = t & 7;
    aqs[r][h] = AQ[(b * H + h) * N + i0 + r] + BF[16 + h] + attn_bp[0];
  }

  const int jm1 = (jl == 0) ? 0 : jl - 1;
  const bool blk0 = (i0 == 0);   // row 0 of this block uses per-lane P1[j-1]
  f32x2 rstd2[4], mb2[4];
#pragma unroll
  for (int r = 0; r < 4; ++r) {
    const int irow = i0 + r;
    const int ip = (irow == 0) ? jm1 : (irow - 1);
    const float rs = RST[ip * N + jm1];
    const float mb = MBP[ip * N + jm1];
    rstd2[r].x = rs; rstd2[r].y = rs;
    mb2[r].x = mb; mb2[r].y = mb;
  }
  float akr[2];
#pragma unroll
  for (int hh = 0; hh < 2; ++hh)
    akr[hh] = AK[(b * H + cq * 2 + hh) * N + jl];
  const f32x2 zero2 = {0.f, 0.f};

  const float4* P14 = reinterpret_cast<const float4*>(ws + WS_P1T);
  const float4* P24 = reinterpret_cast<const float4*>(ws + WS_P2T);
  const int base4 = b * 64 * 128;
  const int c4lo = cq * 16;

  // preload ALL 16 p2 float4 (issue together -> one L2 latency, not 16)
  F4 pp[16];
#pragma unroll
  for (int cc = 0; cc < 16; ++cc)
    pp[cc].v = P24[base4 + (c4lo + cc) * 128 + jm1];

  __syncthreads();

  // loop B (packed, 4 rows): relu(LN(u)) . v2 for 8 heads over 64 channels.
  f32x2 dt2[4][8];
#pragma unroll
  for (int r = 0; r < 4; ++r)
#pragma unroll
    for (int h = 0; h < 8; ++h) dt2[r][h] = zero2;
  for (int cc = 0; cc < 16; ++cc) {
    const int c4 = c4lo + cc;
    F4 p2 = pp[cc];
    F4 g4; g4.v = *(const float4*)&gbs[c4 * 4];
    F4 b4; b4.v = *(const float4*)&gbs[256 + c4 * 4];
    F4 p1r[4];
    if (blk0) p1r[0].v = P14[base4 + c4 * 128 + jm1];
    else      p1r[0].v = *(const float4*)&p1e[0][c4 * 4];
    p1r[1].v = *(const float4*)&p1e[1][c4 * 4];
    p1r[2].v = *(const float4*)&p1e[2][c4 * 4];
    p1r[3].v = *(const float4*)&p1e[3][c4 * 4];
    f32x2 w2[4][2];
#pragma unroll
    for (int r = 0; r < 4; ++r) {
#pragma unroll
      for (int pp2 = 0; pp2 < 2; ++pp2) {
        const f32x2 u2 = p1r[r].h[pp2] + p2.h[pp2];
        const f32x2 zt2 = __builtin_elementwise_fma(u2, rstd2[r], mb2[r]);
        const f32x2 z2 = __builtin_elementwise_fma(zt2, g4.h[pp2], b4.h[pp2]);
        w2[r][pp2] = __builtin_elementwise_max(z2, zero2);
      }
    }
#pragma unroll
    for (int h = 0; h < 8; ++h) {
      F4 v2v; v2v.v = *(const float4*)&v2s[h * D + c4 * 4];
#pragma unroll
      for (int r = 0; r < 4; ++r) {
        dt2[r][h] = __builtin_elementwise_fma(w2[r][0], v2v.h[0], dt2[r][h]);
        dt2[r][h] = __builtin_elementwise_fma(w2[r][1], v2v.h[1], dt2[r][h]);
      }
    }
  }

  // softmax per row (dsh/redm/reds reused; barriers separate the rounds)
  const int w = t >> 6;   // softmax partner wave is w^1 (other jl-half)
  for (int r = 0; r < 4; ++r) {
#pragma unroll
    for (int h = 0; h < 8; ++h) dsh[cq][jl][h] = dt2[r][h].x + dt2[r][h].y;
    __syncthreads();
    const int irow = i0 + r;
    const bool masked = (jl == 0) || (jl == irow);
    float sc[2], pr[2];
#pragma unroll
    for (int hh = 0; hh < 2; ++hh) {
      const int h = cq * 2 + hh;
      const float dsum = dsh[0][jl][h] + dsh[1][jl][h]
                       + dsh[2][jl][h] + dsh[3][jl][h];
      const float v = aqs[r][h] + akr[hh] + dsum;
      sc[hh] = masked ? -INFINITY : v;
    }
    float mx[2];
#pragma unroll
    for (int hh = 0; hh < 2; ++hh) {
      float v = sc[hh];
#pragma unroll
      for (int o = 1; o < 64; o <<= 1) v = fmaxf(v, __shfl_xor(v, o));
      mx[hh] = v;
    }
    if ((t & 63) == 0) { redm[w][0] = mx[0]; redm[w][1] = mx[1]; }
    __syncthreads();
#pragma unroll
    for (int hh = 0; hh < 2; ++hh) {
      const float m = fmaxf(redm[w][hh], redm[w ^ 1][hh]);
      pr[hh] = expf(sc[hh] - m);
    }
    float sm[2];
#pragma unroll
    for (int hh = 0; hh < 2; ++hh) {
      float v = pr[hh];
#pragma unroll
      for (int o = 1; o < 64; o <<= 1) v += __shfl_xor(v, o);
      sm[hh] = v;
    }
    if ((t & 63) == 0) { reds[w][0] = sm[0]; reds[w][1] = sm[1]; }
    __syncthreads();
#pragma unroll
    for (int hh = 0; hh < 2; ++hh) {
      const int h = cq * 2 + hh;
      const float at = pr[hh] / (reds[w][hh] + reds[w ^ 1][hh]);
      attnp[((b * H + h) * N + irow) * N + jl] = at;
    }
    __syncthreads();
  }
}

// K5: ctx = attn @ v ; out = ctx @ wo + bo. grid 256 (XCD-swizzled), 512 thr:
// o4 = t&63 (output channel quad), grp = t>>6 (j-range / c2-range slice).
// All V / wo / attn loads are float4 with ZERO cross-thread duplication;
// partials reduced through LDS (conflict-free stride-16B layout).
__global__ __launch_bounds__(512) void k5_out(
    const float* __restrict__ ws, const float* __restrict__ attnp,
    const float* __restrict__ wo, const float* __restrict__ bo,
    float* __restrict__ outp) {
  const int bid = blockIdx.x;
  const int wg = (bid & 7) * 32 + (bid >> 3);   // bijective; same-b per XCD
  const int b = wg >> 5;
  const int i0 = (wg & 31) * 4;
  const int t = threadIdx.x;
  const int o4 = t & 63;
  const int grp = t >> 6;

  __shared__ float attn_sh[4][H][136];   // pad 136: f4-aligned, low conflict
  __shared__ float red[4][8][64][4];     // [r][grp][o4][e], stride-16B
  __shared__ float ctxs[4][260];

  // stage attn (1024 float4)
#pragma unroll
  for (int k = 0; k < 2; ++k) {
    const int idx = k * 512 + t;
    const int r = idx >> 8, h = (idx >> 5) & 7, j4 = idx & 31;
    const float4 a =
        *(const float4*)&attnp[((b * H + h) * N + i0 + r) * N + j4 * 4];
    *(float4*)&attn_sh[r][h][j4 * 4] = a;
  }
  __syncthreads();

  // ctx partials: this thread covers j in [grp*16, grp*16+16)
  const int hh = o4 >> 3;
  const float* Vb = ws + WS_V + b * N * D;
  F4 acc[4];
#pragma unroll
  for (int r = 0; r < 4; ++r) acc[r].v = make_float4(0.f, 0.f, 0.f, 0.f);
  for (int jj = 0; jj < 16; ++jj) {
    const int j = grp * 16 + jj;
    F4 v4; v4.v = *(const float4*)&Vb[j * D + o4 * 4];
#pragma unroll
    for (int r = 0; r < 4; ++r) {
      const float a = attn_sh[r][hh][j];
#pragma unroll
      for (int e = 0; e < 4; ++e) acc[r].f[e] = fmaf(a, v4.f[e], acc[r].f[e]);
    }
  }
#pragma unroll
  for (int r = 0; r < 4; ++r) *(float4*)&red[r][grp][o4][0] = acc[r].v;
  __syncthreads();
  if (t < 256) {
    const int oc = t & 63, r = t >> 6;
    F4 s; s.v = make_float4(0.f, 0.f, 0.f, 0.f);
#pragma unroll
    for (int g = 0; g < 8; ++g) {
      F4 p; p.v = *(const float4*)&red[r][g][oc][0];
#pragma unroll
      for (int e = 0; e < 4; ++e) s.f[e] += p.f[e];
    }
    *(float4*)&ctxs[r][oc * 4] = s.v;
  }
  __syncthreads();

  // out partials: this thread covers c2 in [grp*32, grp*32+32)
  F4 acc2[4];
#pragma unroll
  for (int r = 0; r < 4; ++r) acc2[r].v = make_float4(0.f, 0.f, 0.f, 0.f);
  for (int cc = 0; cc < 32; ++cc) {
    const int c2 = grp * 32 + cc;
    F4 w4; w4.v = *(const float4*)&wo[c2 * D + o4 * 4];
#pragma unroll
    for (int r = 0; r < 4; ++r) {
      const float cx = ctxs[r][c2];
#pragma unroll
      for (int e = 0; e < 4; ++e)
        acc2[r].f[e] = fmaf(cx, w4.f[e], acc2[r].f[e]);
    }
  }
#pragma unroll
  for (int r = 0; r < 4; ++r) *(float4*)&red[r][grp][o4][0] = acc2[r].v;
  __syncthreads();
  if (t < 256) {
    const int oc = t & 63, r = t >> 6;
    F4 s; s.v = *(const float4*)&bo[oc * 4];
#pragma unroll
    for (int g = 0; g < 8; ++g) {
      F4 p; p.v = *(const float4*)&red[r][g][oc][0];
#pragma unroll
      for (int e = 0; e < 4; ++e) s.f[e] += p.f[e];
    }
    *(float4*)&outp[(b * N + i0 + r) * D + oc * 4] = s.v;
  }
}

extern "C" void kernel_launch(void* const* d_in, const int* in_sizes, int n_in,
                              void* d_out, int out_size, void* d_ws, size_t ws_size,
                              hipStream_t stream) {
  (void)in_sizes; (void)n_in; (void)out_size; (void)ws_size;
  const float* desc = (const float*)d_in[0];
  const float* nv   = (const float*)d_in[1];
  const float* wq   = (const float*)d_in[2];
  const float* bq   = (const float*)d_in[3];
  const float* wk   = (const float*)d_in[4];
  const float* bk   = (const float*)d_in[5];
  const float* wv   = (const float*)d_in[6];
  const float* bv   = (const float*)d_in[7];
  const float* ew1  = (const float*)d_in[8];
  const float* eb1  = (const float*)d_in[9];
  const float* ln_g = (const float*)d_in[10];
  const float* ln_b = (const float*)d_in[11];
  const float* ew2  = (const float*)d_in[12];
  const float* eb2  = (const float*)d_in[13];
  const float* aw   = (const float*)d_in[14];
  const float* ab   = (const float*)d_in[15];
  const float* wo   = (const float*)d_in[16];
  const float* bo   = (const float*)d_in[17];

  float* ws   = (float*)d_ws;
  float* outp = (float*)d_out;
  float* attnp = outp + B * N * D;

  k1_fold<<<25, 256, 0, stream>>>(wq, wk, ew2, bq, bk, eb2, aw, ws);
  kA_pre<<<256, 512, 0, stream>>>(desc, ew1, eb1, nv, wv, bv, ws);
  kG_stats<<<256, 512, 0, stream>>>(ws);
  k4_attn<<<B * 32, 512, 0, stream>>>(ws, ln_g, ln_b, ab, attnp);
  k5_out<<<256, 512, 0, stream>>>(ws, attnp, wo, bo, outp);
}

// Round 19
// 46.727 us; speedup vs baseline: 1.2272x; 1.2272x over previous
//
#include <hip/hip_runtime.h>
#include <math.h>

namespace {
constexpr int D = 256;
constexpr int H = 8;
constexpr int HD = 32;
constexpr int B = 8;
constexpr int S = 127;
constexpr int N = 128;
constexpr float LN_EPS = 1e-5f;

// ws layout (float offsets). P1T/P2T are stored PACKED:
// element (b, c, i) at (b*64 + (c>>2))*512 + i*4 + (c&3)  -> float4 over c for fixed i.
// P1T rows INCLUDE eb1 (folded at kA time).
constexpr int WS_P1T = 0;                  // B*D*N
constexpr int WS_P2T = WS_P1T + B * D * N; // B*D*N
constexpr int WS_V   = WS_P2T + B * D * N; // B*N*D (row-major)
constexpr int WS_AQ  = WS_V + B * N * D;   // B*H*N
constexpr int WS_AK  = WS_AQ + B * H * N;  // B*H*N
constexpr int WS_FQK = WS_AK + B * H * N;  // D*16 (wq-fold | wk-fold)
constexpr int WS_V2  = WS_FQK + D * 16;    // H*D (transposed: [h][c])
constexpr int WS_BF  = WS_V2 + D * H;      // 32 (bq-fold[8], bk-fold[8], be-fold[8])
constexpr int WS_ST  = WS_BF + 32;         // B*4*N row stats: S1,Q1,S2,Q2 (incl eb1 in P1)
constexpr int WS_RSTD = WS_ST + B * 512;   // B*N*N per-pair 1/std
constexpr int WS_MB   = WS_RSTD + B * N * N; // B*N*N per-pair -mean/std

typedef float f32x2 __attribute__((ext_vector_type(2)));
union F4 { float4 v; f32x2 h[2]; float f[4]; };
} // namespace

// K1: fold wq/wk with attn_w[:32]/[32:64] -> FQK (D x 16), ew2 with attn_w[64:96]
// -> V2T (H x D), plus bias folds. Thread-per-output.
__global__ __launch_bounds__(256) void k1_fold(
    const float* __restrict__ wq, const float* __restrict__ wk,
    const float* __restrict__ ew2, const float* __restrict__ bq,
    const float* __restrict__ bk, const float* __restrict__ eb2,
    const float* __restrict__ attn_w, float* __restrict__ ws) {
  float* FQK = ws + WS_FQK;
  float* V2T = ws + WS_V2;
  float* BF  = ws + WS_BF;
  const int tg = blockIdx.x * 256 + threadIdx.x;
  if (tg < 6144) {
    const int mat = tg >> 11;
    const int rem = tg & 2047;
    const int c = rem >> 3;
    const int h = rem & 7;
    const float* W = (mat == 0) ? wq : (mat == 1) ? wk : ew2;
    const float* aw = attn_w + mat * HD;
    const float* wrow = W + c * D + h * HD;
    float s = 0.f;
#pragma unroll
    for (int d = 0; d < HD; ++d) s = fmaf(wrow[d], aw[d], s);
    if (mat < 2) FQK[c * 16 + mat * 8 + h] = s;
    else         V2T[h * D + c] = s;
  } else if (tg < 6168) {
    const int idx = tg - 6144;
    const int mat = idx >> 3;
    const int h = idx & 7;
    const float* bias = (mat == 0) ? bq : (mat == 1) ? bk : eb2;
    const float* aw = attn_w + mat * HD;
    float s = 0.f;
#pragma unroll
    for (int d = 0; d < HD; ++d) s = fmaf(bias[h * HD + d], aw[d], s);
    BF[mat * 8 + h] = s;
  }
}

// KA: role 0 (blocks 0..127): 8 desc rows/block -> P1/P2 packed (+eb1 into P1)
// + row stats. Thread = (o4, {m, c2-quarter}); each wave's 64 float4 ew1 loads
// serve 8 rows. Partials LDS-reduced in two barrier rounds (m=0, m=1); stats
// via one-wave-per-row shfl.
// role 1 (blocks 128..255): 8 nv rows/block -> V (waves 0-3, channel-split wv)
// + aq/ak (waves 4-7, FQK in LDS).
__global__ __launch_bounds__(512) void kA_pre(
    const float* __restrict__ desc, const float* __restrict__ ew1,
    const float* __restrict__ eb1,
    const float* __restrict__ nv, const float* __restrict__ wv,
    const float* __restrict__ bv, float* __restrict__ ws) {
  const int blk = blockIdx.x;
  const int t = threadIdx.x;
  __shared__ float rows[8][264];          // 8.4 KB
  __shared__ float red[8][4][64][4];      // 32 KB
  __shared__ float fqks[D * 16];          // 16 KB (role 1)
  __shared__ float aqred2[2][128];

  if (blk < 128) {
    // ---- role 0 ----
    float* P1Tf = ws + WS_P1T;
    float* P2Tf = ws + WS_P2T;
    const int b = blk >> 4;
    const int i0 = (blk & 15) * 8;
    {
      const int r = t >> 6, c4 = t & 63;
      const int row = i0 + r;
      F4 dv;
      if (row < S) dv.v = *(const float4*)&desc[(b * S + row) * D + c4 * 4];
      else         dv.v = make_float4(0.f, 0.f, 0.f, 0.f);
      *(float4*)&rows[r][c4 * 4] = dv.v;
    }
    __syncthreads();
    const int o4 = t & 63;
    const int grp = t >> 6;
    const int m = grp >> 2;          // 0: ew1[:D] (P1), 1: ew1[D:] (P2)
    const int q = grp & 3;           // c2 quarter
    const float* W = ew1 + m * D * D;
    F4 acc[8];
#pragma unroll
    for (int r = 0; r < 8; ++r) acc[r].v = make_float4(0.f, 0.f, 0.f, 0.f);
    for (int cc = 0; cc < 64; ++cc) {
      const int c2 = q * 64 + cc;
      F4 w; w.v = *(const float4*)&W[c2 * D + o4 * 4];
#pragma unroll
      for (int r = 0; r < 8; ++r) {
        const float s = rows[r][c2];
#pragma unroll
        for (int e = 0; e < 4; ++e) acc[r].f[e] = fmaf(s, w.f[e], acc[r].f[e]);
      }
    }
#pragma unroll
    for (int mm = 0; mm < 2; ++mm) {
      if (m == mm) {
#pragma unroll
        for (int r = 0; r < 8; ++r) *(float4*)&red[r][q][o4][0] = acc[r].v;
      }
      __syncthreads();
      {
        const int r = t >> 6;        // one wave per row; lane = o4
        F4 s; s.v = make_float4(0.f, 0.f, 0.f, 0.f);
#pragma unroll
        for (int g = 0; g < 4; ++g) {
          F4 p; p.v = *(const float4*)&red[r][g][o4][0];
#pragma unroll
          for (int e = 0; e < 4; ++e) s.f[e] += p.f[e];
        }
        if (mm == 0) {
          F4 eb; eb.v = *(const float4*)&eb1[o4 * 4];
#pragma unroll
          for (int e = 0; e < 4; ++e) s.f[e] += eb.f[e];
        }
        const int row = i0 + r;
        float* PT = (mm == 0) ? P1Tf : P2Tf;
        if (row < S) *(float4*)&PT[(b * 64 + o4) * 512 + row * 4] = s.v;
        float sv = 0.f, qv = 0.f;
#pragma unroll
        for (int e = 0; e < 4; ++e) {
          sv += s.f[e];
          qv = fmaf(s.f[e], s.f[e], qv);
        }
#pragma unroll
        for (int o = 1; o < 64; o <<= 1) {
          sv += __shfl_xor(sv, o);
          qv += __shfl_xor(qv, o);
        }
        if (o4 == 0 && row < S) {
          float* STW = ws + WS_ST + b * 512 + mm * 256;
          STW[row] = sv;
          STW[128 + row] = qv;
        }
      }
      __syncthreads();
    }
  } else {
    // ---- role 1 ----
    float* Vf  = ws + WS_V;
    float* AQ  = ws + WS_AQ;
    float* AK  = ws + WS_AK;
    const float* BF = ws + WS_BF;
    const int blk2 = blk - 128;
    const int b = blk2 >> 4;
    const int j0 = (blk2 & 15) * 8;
    {
      const int r = t >> 6, c4 = t & 63;
      *(float4*)&rows[r][c4 * 4] =
          *(const float4*)&nv[(b * N + j0 + r) * D + c4 * 4];
      float4* fq4 = (float4*)fqks;
      const float4* FQK4 = (const float4*)(ws + WS_FQK);
      fq4[t] = FQK4[t];
      fq4[512 + t] = FQK4[512 + t];
    }
    __syncthreads();
    if (t < 256) {
      // waves 0-3: V = nv @ wv partials (channel quarter q)
      const int o4 = t & 63, q = t >> 6;
      F4 acc[8];
#pragma unroll
      for (int r = 0; r < 8; ++r) acc[r].v = make_float4(0.f, 0.f, 0.f, 0.f);
      for (int cc = 0; cc < 64; ++cc) {
        const int c2 = q * 64 + cc;
        F4 w; w.v = *(const float4*)&wv[c2 * D + o4 * 4];
#pragma unroll
        for (int r = 0; r < 8; ++r) {
          const float s = rows[r][c2];
#pragma unroll
          for (int e = 0; e < 4; ++e)
            acc[r].f[e] = fmaf(s, w.f[e], acc[r].f[e]);
        }
      }
#pragma unroll
      for (int r = 0; r < 8; ++r) *(float4*)&red[r][q][o4][0] = acc[r].v;
    } else {
      // waves 4-7: aq/ak via LDS FQK
      const int idx = t - 256;
      const int il = idx >> 5;           // row 0..7
      const int oi = idx & 15;           // output (aq|ak)
      const int ch = (idx >> 4) & 1;     // channel half
      float s = 0.f;
      for (int c = ch * 128; c < ch * 128 + 128; ++c)
        s = fmaf(rows[il][c], fqks[c * 16 + oi], s);
      aqred2[ch][il * 16 + oi] = s;
    }
    __syncthreads();
    {
      const int r = t >> 6, o4 = t & 63;
      F4 s; s.v = make_float4(0.f, 0.f, 0.f, 0.f);
#pragma unroll
      for (int g = 0; g < 4; ++g) {
        F4 p; p.v = *(const float4*)&red[r][g][o4][0];
#pragma unroll
        for (int e = 0; e < 4; ++e) s.f[e] += p.f[e];
      }
      F4 b4; b4.v = *(const float4*)&bv[o4 * 4];
#pragma unroll
      for (int e = 0; e < 4; ++e) s.f[e] += b4.f[e];
      *(float4*)&Vf[(b * N + j0 + r) * D + o4 * 4] = s.v;
    }
    if (t < 128) {
      const int il = t >> 4, oi = t & 15;
      const float s2 = aqred2[0][t] + aqred2[1][t] + BF[oi];
      if (oi < 8) AQ[(b * H + oi) * N + j0 + il] = s2;
      else        AK[(b * H + (oi - 8)) * N + j0 + il] = s2;
    }
  }
}

// KG: G = P1 . P2 per (ip,jp) pair via reg-cached P2 slices, then fold with
// row stats ST into per-pair rstd / mB. grid 256 (XCD-swizzled), 512 threads.
__global__ __launch_bounds__(512) void kG_stats(float* __restrict__ ws) {
  const int bid = blockIdx.x;
  const int wg = (bid & 7) * 32 + (bid >> 3);   // one b per XCD
  const int b = wg >> 5;
  const int ip0 = (wg & 31) * 4;
  const int t = threadIdx.x;
  const int jp = t & 127;
  const int cg = t >> 7;

  __shared__ float p1t[1024];        // [4][256]
  __shared__ float gred[4][4][128];  // [cg][r][jp]

  const float* P1Tf = ws + WS_P1T;
  const float4* P24 = reinterpret_cast<const float4*>(ws + WS_P2T);
  const float* ST = ws + WS_ST + b * 512;
  float* RST = ws + WS_RSTD + b * N * N;
  float* MBP = ws + WS_MB + b * N * N;
  const int base4 = b * 64 * 128;

  for (int k = t; k < 1024; k += 512) {
    const int r = k >> 8, c = k & 255;
    const int row = ip0 + r;
    p1t[r * 256 + c] = (row < S)
        ? P1Tf[(b * 64 + (c >> 2)) * 512 + row * 4 + (c & 3)] : 0.f;
  }
  F4 pp[16];
#pragma unroll
  for (int cc = 0; cc < 16; ++cc)
    pp[cc].v = P24[base4 + (cg * 16 + cc) * 128 + jp];
  __syncthreads();

  float g[4] = {0.f, 0.f, 0.f, 0.f};
#pragma unroll
  for (int cc = 0; cc < 16; ++cc) {
    const int c4 = cg * 16 + cc;
#pragma unroll
    for (int r = 0; r < 4; ++r) {
      F4 p1; p1.v = *(const float4*)&p1t[r * 256 + c4 * 4];
      g[r] = fmaf(pp[cc].f[0], p1.f[0], g[r]);
      g[r] = fmaf(pp[cc].f[1], p1.f[1], g[r]);
      g[r] = fmaf(pp[cc].f[2], p1.f[2], g[r]);
      g[r] = fmaf(pp[cc].f[3], p1.f[3], g[r]);
    }
  }
#pragma unroll
  for (int r = 0; r < 4; ++r) gred[cg][r][jp] = g[r];
  __syncthreads();
  {
    const int r2 = t >> 7, jp2 = t & 127;
    const float G = gred[0][r2][jp2] + gred[1][r2][jp2]
                  + gred[2][r2][jp2] + gred[3][r2][jp2];
    const int ip = ip0 + r2;
    const float S1 = ST[0 * 128 + ip], Q1 = ST[1 * 128 + ip];
    const float S2 = ST[2 * 128 + jp2], Q2 = ST[3 * 128 + jp2];
    const float mean = (S1 + S2) * (1.f / 256.f);
    const float var = (Q1 + Q2 + 2.f * G) * (1.f / 256.f) - mean * mean;
    const float rstd = 1.f / sqrtf(var + LN_EPS);
    RST[ip * N + jp2] = rstd;
    MBP[ip * N + jp2] = -mean * rstd;
  }
}

// K4: edge-MLP dot -> scores -> softmax -> attn write.
// grid B*32 (XCD-swizzled): block = (b, 4-row i-tile). 512 threads:
// jl = t&127 (column j), cq = t>>7 (channel quarter; heads {2cq,2cq+1} for
// softmax). v2/ln staged in LDS; p2 the only per-iter VMEM load; operand
// fetches amortize over 4 rows. Packed fp32 math (v_pk_*).
// R14 configuration — measured best (47.1 us total); R16/R17/R18 variants
// (v2 split, Itile 2, p2 reg-preload) all regressed.
__global__ __launch_bounds__(512) void k4_attn(
    const float* __restrict__ ws,
    const float* __restrict__ ln_g, const float* __restrict__ ln_b,
    const float* __restrict__ attn_bp, float* __restrict__ attnp) {
  const int bid = blockIdx.x;
  const int wg = (bid & 7) * 32 + (bid >> 3);   // bijective; one b per XCD
  const int b = wg >> 5;
  const int i0 = (wg & 31) * 4;
  const int t = threadIdx.x;
  const int jl = t & 127;
  const int cq = t >> 7;

  __shared__ float v2s[H * D];       // 8 KB
  __shared__ float gbs[2 * D];       // 2 KB (ln_g | ln_b)
  __shared__ float p1e[4][D];        // 4 KB
  __shared__ float dsh[4][128][9];   // 18 KB, stride 9 = conflict-free
  __shared__ float aqs[4][8];
  __shared__ float redm[8][2], reds[8][2];

  const float* P1Tf = ws + WS_P1T;
  const float* AQ   = ws + WS_AQ;
  const float* AK   = ws + WS_AK;
  const float* BF   = ws + WS_BF;
  const float* v2p  = ws + WS_V2;
  const float* RST  = ws + WS_RSTD + b * N * N;
  const float* MBP  = ws + WS_MB + b * N * N;

  // stage uniform operands into LDS
  reinterpret_cast<float4*>(v2s)[t] = reinterpret_cast<const float4*>(v2p)[t];
  if (t < 256) { gbs[t] = ln_g[t]; gbs[256 + t] = ln_b[t]; }
  for (int k = t; k < 4 * D; k += 512) {
    const int r = k >> 8, c = k & 255;
    const int row = i0 + r - 1;
    p1e[r][c] = (row >= 0)
        ? P1Tf[(b * 64 + (c >> 2)) * 512 + row * 4 + (c & 3)] : 0.f;
  }
  if (t < 32) {
    const int r = t >> 3, h = t & 7;
    aqs[r][h] = AQ[(b * H + h) * N + i0 + r] + BF[16 + h] + attn_bp[0];
  }

  const int jm1 = (jl == 0) ? 0 : jl - 1;
  const bool blk0 = (i0 == 0);   // row 0 of this block uses per-lane P1[j-1]
  f32x2 rstd2[4], mb2[4];
#pragma unroll
  for (int r = 0; r < 4; ++r) {
    const int irow = i0 + r;
    const int ip = (irow == 0) ? jm1 : (irow - 1);
    const float rs = RST[ip * N + jm1];
    const float mb = MBP[ip * N + jm1];
    rstd2[r].x = rs; rstd2[r].y = rs;
    mb2[r].x = mb; mb2[r].y = mb;
  }
  float akr[2];
#pragma unroll
  for (int hh = 0; hh < 2; ++hh)
    akr[hh] = AK[(b * H + cq * 2 + hh) * N + jl];
  const f32x2 zero2 = {0.f, 0.f};
  __syncthreads();

  const float4* P14 = reinterpret_cast<const float4*>(ws + WS_P1T);
  const float4* P24 = reinterpret_cast<const float4*>(ws + WS_P2T);
  const int base4 = b * 64 * 128;
  const int c4lo = cq * 16;

  // loop B (packed, 4 rows): relu(LN(u)) . v2 for 8 heads over 64 channels.
  f32x2 dt2[4][8];
#pragma unroll
  for (int r = 0; r < 4; ++r)
#pragma unroll
    for (int h = 0; h < 8; ++h) dt2[r][h] = zero2;
  F4 p2c;
  p2c.v = P24[base4 + c4lo * 128 + jm1];
  for (int cc = 0; cc < 16; ++cc) {
    const int c4 = c4lo + cc;
    F4 p2 = p2c;
    if (cc < 15) p2c.v = P24[base4 + (c4 + 1) * 128 + jm1];
    F4 g4; g4.v = *(const float4*)&gbs[c4 * 4];
    F4 b4; b4.v = *(const float4*)&gbs[256 + c4 * 4];
    F4 p1r[4];
    if (blk0) p1r[0].v = P14[base4 + c4 * 128 + jm1];
    else      p1r[0].v = *(const float4*)&p1e[0][c4 * 4];
    p1r[1].v = *(const float4*)&p1e[1][c4 * 4];
    p1r[2].v = *(const float4*)&p1e[2][c4 * 4];
    p1r[3].v = *(const float4*)&p1e[3][c4 * 4];
    f32x2 w2[4][2];
#pragma unroll
    for (int r = 0; r < 4; ++r) {
#pragma unroll
      for (int pp = 0; pp < 2; ++pp) {
        const f32x2 u2 = p1r[r].h[pp] + p2.h[pp];
        const f32x2 zt2 = __builtin_elementwise_fma(u2, rstd2[r], mb2[r]);
        const f32x2 z2 = __builtin_elementwise_fma(zt2, g4.h[pp], b4.h[pp]);
        w2[r][pp] = __builtin_elementwise_max(z2, zero2);
      }
    }
#pragma unroll
    for (int h = 0; h < 8; ++h) {
      F4 v2v; v2v.v = *(const float4*)&v2s[h * D + c4 * 4];
#pragma unroll
      for (int r = 0; r < 4; ++r) {
        dt2[r][h] = __builtin_elementwise_fma(w2[r][0], v2v.h[0], dt2[r][h]);
        dt2[r][h] = __builtin_elementwise_fma(w2[r][1], v2v.h[1], dt2[r][h]);
      }
    }
  }

  // softmax per row (dsh/redm/reds reused; barriers separate the rounds)
  const int w = t >> 6;   // softmax partner wave is w^1 (other jl-half)
  for (int r = 0; r < 4; ++r) {
#pragma unroll
    for (int h = 0; h < 8; ++h) dsh[cq][jl][h] = dt2[r][h].x + dt2[r][h].y;
    __syncthreads();
    const int irow = i0 + r;
    const bool masked = (jl == 0) || (jl == irow);
    float sc[2], pr[2];
#pragma unroll
    for (int hh = 0; hh < 2; ++hh) {
      const int h = cq * 2 + hh;
      const float dsum = dsh[0][jl][h] + dsh[1][jl][h]
                       + dsh[2][jl][h] + dsh[3][jl][h];
      const float v = aqs[r][h] + akr[hh] + dsum;
      sc[hh] = masked ? -INFINITY : v;
    }
    float mx[2];
#pragma unroll
    for (int hh = 0; hh < 2; ++hh) {
      float v = sc[hh];
#pragma unroll
      for (int o = 1; o < 64; o <<= 1) v = fmaxf(v, __shfl_xor(v, o));
      mx[hh] = v;
    }
    if ((t & 63) == 0) { redm[w][0] = mx[0]; redm[w][1] = mx[1]; }
    __syncthreads();
#pragma unroll
    for (int hh = 0; hh < 2; ++hh) {
      const float m = fmaxf(redm[w][hh], redm[w ^ 1][hh]);
      pr[hh] = expf(sc[hh] - m);
    }
    float sm[2];
#pragma unroll
    for (int hh = 0; hh < 2; ++hh) {
      float v = pr[hh];
#pragma unroll
      for (int o = 1; o < 64; o <<= 1) v += __shfl_xor(v, o);
      sm[hh] = v;
    }
    if ((t & 63) == 0) { reds[w][0] = sm[0]; reds[w][1] = sm[1]; }
    __syncthreads();
#pragma unroll
    for (int hh = 0; hh < 2; ++hh) {
      const int h = cq * 2 + hh;
      const float at = pr[hh] / (reds[w][hh] + reds[w ^ 1][hh]);
      attnp[((b * H + h) * N + irow) * N + jl] = at;
    }
    __syncthreads();
  }
}

// K5: ctx = attn @ v ; out = ctx @ wo + bo. grid 256 (XCD-swizzled), 512 thr:
// o4 = t&63 (output channel quad), grp = t>>6 (j-range / c2-range slice).
// All V / wo / attn loads are float4 with ZERO cross-thread duplication;
// partials reduced through LDS (conflict-free stride-16B layout).
__global__ __launch_bounds__(512) void k5_out(
    const float* __restrict__ ws, const float* __restrict__ attnp,
    const float* __restrict__ wo, const float* __restrict__ bo,
    float* __restrict__ outp) {
  const int bid = blockIdx.x;
  const int wg = (bid & 7) * 32 + (bid >> 3);   // bijective; same-b per XCD
  const int b = wg >> 5;
  const int i0 = (wg & 31) * 4;
  const int t = threadIdx.x;
  const int o4 = t & 63;
  const int grp = t >> 6;

  __shared__ float attn_sh[4][H][136];   // pad 136: f4-aligned, low conflict
  __shared__ float red[4][8][64][4];     // [r][grp][o4][e], stride-16B
  __shared__ float ctxs[4][260];

  // stage attn (1024 float4)
#pragma unroll
  for (int k = 0; k < 2; ++k) {
    const int idx = k * 512 + t;
    const int r = idx >> 8, h = (idx >> 5) & 7, j4 = idx & 31;
    const float4 a =
        *(const float4*)&attnp[((b * H + h) * N + i0 + r) * N + j4 * 4];
    *(float4*)&attn_sh[r][h][j4 * 4] = a;
  }
  __syncthreads();

  // ctx partials: this thread covers j in [grp*16, grp*16+16)
  const int hh = o4 >> 3;
  const float* Vb = ws + WS_V + b * N * D;
  F4 acc[4];
#pragma unroll
  for (int r = 0; r < 4; ++r) acc[r].v = make_float4(0.f, 0.f, 0.f, 0.f);
  for (int jj = 0; jj < 16; ++jj) {
    const int j = grp * 16 + jj;
    F4 v4; v4.v = *(const float4*)&Vb[j * D + o4 * 4];
#pragma unroll
    for (int r = 0; r < 4; ++r) {
      const float a = attn_sh[r][hh][j];
#pragma unroll
      for (int e = 0; e < 4; ++e) acc[r].f[e] = fmaf(a, v4.f[e], acc[r].f[e]);
    }
  }
#pragma unroll
  for (int r = 0; r < 4; ++r) *(float4*)&red[r][grp][o4][0] = acc[r].v;
  __syncthreads();
  if (t < 256) {
    const int oc = t & 63, r = t >> 6;
    F4 s; s.v = make_float4(0.f, 0.f, 0.f, 0.f);
#pragma unroll
    for (int g = 0; g < 8; ++g) {
      F4 p; p.v = *(const float4*)&red[r][g][oc][0];
#pragma unroll
      for (int e = 0; e < 4; ++e) s.f[e] += p.f[e];
    }
    *(float4*)&ctxs[r][oc * 4] = s.v;
  }
  __syncthreads();

  // out partials: this thread covers c2 in [grp*32, grp*32+32)
  F4 acc2[4];
#pragma unroll
  for (int r = 0; r < 4; ++r) acc2[r].v = make_float4(0.f, 0.f, 0.f, 0.f);
  for (int cc = 0; cc < 32; ++cc) {
    const int c2 = grp * 32 + cc;
    F4 w4; w4.v = *(const float4*)&wo[c2 * D + o4 * 4];
#pragma unroll
    for (int r = 0; r < 4; ++r) {
      const float cx = ctxs[r][c2];
#pragma unroll
      for (int e = 0; e < 4; ++e)
        acc2[r].f[e] = fmaf(cx, w4.f[e], acc2[r].f[e]);
    }
  }
#pragma unroll
  for (int r = 0; r < 4; ++r) *(float4*)&red[r][grp][o4][0] = acc2[r].v;
  __syncthreads();
  if (t < 256) {
    const int oc = t & 63, r = t >> 6;
    F4 s; s.v = *(const float4*)&bo[oc * 4];
#pragma unroll
    for (int g = 0; g < 8; ++g) {
      F4 p; p.v = *(const float4*)&red[r][g][oc][0];
#pragma unroll
      for (int e = 0; e < 4; ++e) s.f[e] += p.f[e];
    }
    *(float4*)&outp[(b * N + i0 + r) * D + oc * 4] = s.v;
  }
}

extern "C" void kernel_launch(void* const* d_in, const int* in_sizes, int n_in,
                              void* d_out, int out_size, void* d_ws, size_t ws_size,
                              hipStream_t stream) {
  (void)in_sizes; (void)n_in; (void)out_size; (void)ws_size;
  const float* desc = (const float*)d_in[0];
  const float* nv   = (const float*)d_in[1];
  const float* wq   = (const float*)d_in[2];
  const float* bq   = (const float*)d_in[3];
  const float* wk   = (const float*)d_in[4];
  const float* bk   = (const float*)d_in[5];
  const float* wv   = (const float*)d_in[6];
  const float* bv   = (const float*)d_in[7];
  const float* ew1  = (const float*)d_in[8];
  const float* eb1  = (const float*)d_in[9];
  const float* ln_g = (const float*)d_in[10];
  const float* ln_b = (const float*)d_in[11];
  const float* ew2  = (const float*)d_in[12];
  const float* eb2  = (const float*)d_in[13];
  const float* aw   = (const float*)d_in[14];
  const float* ab   = (const float*)d_in[15];
  const float* wo   = (const float*)d_in[16];
  const float* bo   = (const float*)d_in[17];

  float* ws   = (float*)d_ws;
  float* outp = (float*)d_out;
  float* attnp = outp + B * N * D;

  k1_fold<<<25, 256, 0, stream>>>(wq, wk, ew2, bq, bk, eb2, aw, ws);
  kA_pre<<<256, 512, 0, stream>>>(desc, ew1, eb1, nv, wv, bv, ws);
  kG_stats<<<256, 512, 0, stream>>>(ws);
  k4_attn<<<B * 32, 512, 0, stream>>>(ws, ln_g, ln_b, ab, attnp);
  k5_out<<<256, 512, 0, stream>>>(ws, attnp, wo, bo, outp);
}